// Round 10
// baseline (61712.628 us; speedup 1.0000x reference)
//
#include <hip/hip_runtime.h>
#include <math.h>

#define TSTEPS 512
#define NBATCH 256
#define DLL 300
#define DAA 74
#define DVV 35
#define DX  409
#define DH  128
#define DMEM 256
#define CST 768   // 6*DH

typedef unsigned short u16;
typedef unsigned int   u32;
typedef float v2f __attribute__((ext_vector_type(2)));

__device__ __forceinline__ float ulo(u32 u){ return __uint_as_float(u<<16); }
__device__ __forceinline__ float uhi(u32 u){ return __uint_as_float(u & 0xffff0000u); }
__device__ __forceinline__ float sigf(float x){ return 1.0f/(1.0f+expf(-x)); }

// 8k-tiled: dst[(kb*OUT + o)*8 + j] = bf16(src[o*IN + kb*8+j]) or 0 pad
__global__ void cast_tile8(const float* __restrict__ src, u16* __restrict__ dst,
                           int OUT, int IN, int INP){
  int e = blockIdx.x*blockDim.x + threadIdx.x;
  if (e >= OUT*INP) return;
  int j = e & 7;
  int q = e >> 3;
  int o = q % OUT;
  int kb = q / OUT;
  int k = kb*8 + j;
  float v = (k < IN) ? src[o*IN + k] : 0.f;
  u32 u = __float_as_uint(v);
  u32 r = (u + 0x7fffu + ((u>>16)&1u)) >> 16;   // RNE
  dst[e] = (u16)r;
}

struct P {
  const float* x;
  const float *bih_l,*bhh_l,*bih_a,*bhh_a,*bih_v,*bhh_v;
  const float *a1b1,*a1b2,*a2b1,*a2b2,*g1b1,*g1b2,*g2b1,*g2b2;
  const float *ob1,*ow2,*ob2;
  const u16 *ihl,*hhl,*iha,*hha,*ihv,*hhv;
  const u16 *a1w1,*a1w2,*a2w1,*a2w2,*g1w1,*g1w2,*g2w1,*g2w2,*ow1;
  float* out;
};

// one 8k tile: 8 bf16 weights (one col) x acts[16] (8k x 2 rows interleaved) -> 2 accs
__device__ __forceinline__ void kb16(uint4 w, const float* __restrict__ ap,
                                     float &a0, float &a1){
  float4 x0=*(const float4*)ap, x1=*(const float4*)(ap+4),
         x2=*(const float4*)(ap+8), x3=*(const float4*)(ap+12);
  a0 += x0.x*ulo(w.x); a1 += x0.y*ulo(w.x);
  a0 += x0.z*uhi(w.x); a1 += x0.w*uhi(w.x);
  a0 += x1.x*ulo(w.y); a1 += x1.y*ulo(w.y);
  a0 += x1.z*uhi(w.y); a1 += x1.w*uhi(w.y);
  a0 += x2.x*ulo(w.z); a1 += x2.y*ulo(w.z);
  a0 += x2.z*uhi(w.z); a1 += x2.w*uhi(w.z);
  a0 += x3.x*ulo(w.w); a1 += x3.y*ulo(w.w);
  a0 += x3.z*uhi(w.w); a1 += x3.w*uhi(w.w);
}

// 8-deep weight-prefetch ring (two 4-tile groups in flight ahead of compute).
// NKB must be a multiple of 4, NKB >= 8. Loads for a group are issued two
// loop iterations before their compute -> waitcnt slack ~2x compute time.
template<int NKB, int WS>
__device__ __forceinline__ void sweep(const uint4* __restrict__ wp,
                                      const float* __restrict__ base,
                                      float &a0, float &a1){
  uint4 w0=wp[0],    w1=wp[WS],   w2=wp[2*WS], w3=wp[3*WS];
  uint4 v0=wp[4*WS], v1=wp[5*WS], v2=wp[6*WS], v3=wp[7*WS];
  const uint4* wn = wp + 8*WS;
  #pragma unroll 1
  for (int kb=0; kb+8<NKB; kb+=4){
    uint4 n0=wn[0], n1=wn[WS], n2=wn[2*WS], n3=wn[3*WS]; wn += 4*WS;
    kb16(w0, base+kb*16,    a0,a1);
    kb16(w1, base+kb*16+16, a0,a1);
    kb16(w2, base+kb*16+32, a0,a1);
    kb16(w3, base+kb*16+48, a0,a1);
    w0=v0; w1=v1; w2=v2; w3=v3;
    v0=n0; v1=n1; v2=n2; v3=n3;
  }
  kb16(w0, base+(NKB-8)*16,    a0,a1);
  kb16(w1, base+(NKB-7)*16,    a0,a1);
  kb16(w2, base+(NKB-6)*16,    a0,a1);
  kb16(w3, base+(NKB-5)*16,    a0,a1);
  kb16(v0, base+(NKB-4)*16,    a0,a1);
  kb16(v1, base+(NKB-3)*16,    a0,a1);
  kb16(v2, base+(NKB-2)*16,    a0,a1);
  kb16(v3, base+(NKB-1)*16,    a0,a1);
}

// padded x index -> feature index (or -1 for pad). L:[0,320) A:[320,416) V:[416,480)
__device__ __forceinline__ int xfeat(int i){
  if (i < 300) return i;
  if (i < 320) return -1;
  if (i < 394) return i-20;
  if (i < 416) return -1;
  if (i < 451) return i-42;
  return -1;
}

__global__ void __launch_bounds__(512, 2)
mfn_persistent(P p){
  __shared__ __align__(16) float s_x2[960];      // [i*2+r], i<480 padded (pads stay 0)
  __shared__ __align__(16) float s_h2[3][256];   // [m][u*2+r]
  __shared__ __align__(16) float s_c2[3][256];
  __shared__ __align__(16) float s_cstar[1536];  // [idx*2+r]
  __shared__ __align__(16) float s_z[512];       // [k*2+r]
  __shared__ __align__(16) float s_attm[2048];   // [idx*2+r], idx<1024 (att768|mem256)
  __shared__ __align__(16) float s_z2[1536];     // [(mat*256+col)*2+r]
  __shared__ __align__(16) float s_mem[512];     // [r*256+col]
  __shared__ __align__(16) float s_p[3072];      // gates / partials
  __shared__ __align__(16) float s_last[1280];   // [j*2+r]
  __shared__ __align__(16) float s_a1b1[256];
  __shared__ __align__(16) float s_a1b2[768];
  __shared__ __align__(16) float s_b6[6][256];   // a2b1,g1b1,g2b1,a2b2,g1b2,g2b2
  __shared__ float s_red[16];

  const int tid = threadIdx.x;
  const int n0  = blockIdx.x*2;
  const int col = tid&255, rr = tid>>8, kh = tid>>8;

  // LSTM biases in registers (1 col/thread in P1)
  const float bLg = p.bih_l[tid]+p.bhh_l[tid];
  const float bAg = p.bih_a[tid]+p.bhh_a[tid];
  const float bVg = p.bih_v[tid]+p.bhh_v[tid];

  // ---- init ----
  if (tid < 256){
    s_a1b1[tid]=p.a1b1[tid];
    s_b6[0][tid]=p.a2b1[tid]; s_b6[1][tid]=p.g1b1[tid]; s_b6[2][tid]=p.g2b1[tid];
    s_b6[3][tid]=p.a2b2[tid]; s_b6[4][tid]=p.g1b2[tid]; s_b6[5][tid]=p.g2b2[tid];
  }
  for (int i=tid;i<768;i+=512){
    s_a1b2[i]=p.a1b2[i];
    (&s_h2[0][0])[i]=0.f; (&s_c2[0][0])[i]=0.f;
  }
  s_mem[tid]=0.f;
  for (int i2=tid;i2<960;i2+=512){
    float v=0.f; int f=xfeat(i2>>1);
    if (f>=0) v = p.x[(size_t)(n0+(i2&1))*DX + f];
    s_x2[i2]=v;
  }
  __syncthreads();

  for (int t=0; t<TSTEPS; t++){
    // ================ P1: LSTM gates (1 col/thread, coherent full-K sweeps) ========
    {
      float a0,a1;
      a0=0.f; a1=0.f;
      sweep<40,512>((const uint4*)p.ihl + tid, &s_x2[0],   a0,a1);
      sweep<16,512>((const uint4*)p.hhl + tid, &s_h2[0][0],a0,a1);
      *(v2f*)&s_p[tid*2] = (v2f){a0+bLg, a1+bLg};
      a0=0.f; a1=0.f;
      sweep<12,512>((const uint4*)p.iha + tid, &s_x2[640], a0,a1);
      sweep<16,512>((const uint4*)p.hha + tid, &s_h2[1][0],a0,a1);
      *(v2f*)&s_p[1024 + tid*2] = (v2f){a0+bAg, a1+bAg};
      a0=0.f; a1=0.f;
      sweep< 8,512>((const uint4*)p.ihv + tid, &s_x2[832], a0,a1);
      sweep<16,512>((const uint4*)p.hhv + tid, &s_h2[2][0],a0,a1);
      *(v2f*)&s_p[2048 + tid*2] = (v2f){a0+bVg, a1+bVg};
    }
    __syncthreads();                               // B1

    // ================ P2: LSTM activations (768 tasks) ================
    for (int task=tid; task<768; task+=512){
      int m=task>>8, rem=task&255, u=rem>>1, r=rem&1;
      const float* pm = s_p + m*1024;
      float g0 = pm[u*2+r];
      float g1 = pm[(128+u)*2+r];
      float g2 = pm[(256+u)*2+r];
      float g3 = pm[(384+u)*2+r];
      float ig=sigf(g0), fg=sigf(g1), gg=tanhf(g2), og=sigf(g3);
      float co=s_c2[m][u*2+r];
      float c = fg*co + ig*gg;
      float h = og*tanhf(c);
      s_c2[m][u*2+r]=c; s_h2[m][u*2+r]=h;
      s_cstar[(m*128+u)*2+r]     = co;
      s_cstar[(384+m*128+u)*2+r] = c;
    }
    __syncthreads();                               // B2

    // ================ P3: att1_W1 (K=768, OUT=256, 2-way kh split) ================
    {
      float a0=0.f,a1=0.f;
      sweep<48,256>((const uint4*)p.a1w1 + (kh*48*256 + col), &s_cstar[kh*768], a0,a1);
      *(v2f*)&s_p[kh*512 + col*2] = (v2f){a0,a1};
    }
    __syncthreads();                               // B3

    // ================ P4: z1 finalize ================
    {
      float z = s_a1b1[col] + s_p[col*2+rr] + s_p[512+col*2+rr];
      s_z[col*2+rr] = fmaxf(z,0.f);
    }
    __syncthreads();                               // B4

    // ================ P5: att1_W2 (K=256, OUT=768; 3 sequential col-streams) ========
    {
      const uint4* wb=(const uint4*)p.a1w2 + (kh*16*768 + col);
      const float* base=&s_z[kh*256];
      float a0=0.f,a1=0.f,b0=0.f,b1=0.f,c0=0.f,c1=0.f;
      sweep<16,768>(wb,     base, a0,a1);
      sweep<16,768>(wb+256, base, b0,b1);
      sweep<16,768>(wb+512, base, c0,c1);
      *(v2f*)&s_p[kh*1536 + col*2]         = (v2f){a0,a1};
      *(v2f*)&s_p[kh*1536 + (256+col)*2]   = (v2f){b0,b1};
      *(v2f*)&s_p[kh*1536 + (512+col)*2]   = (v2f){c0,c1};
    }
    __syncthreads();                               // B5

    // ================ softmax + attended ================
    {
      float s0 = s_a1b2[col]     + s_p[col*2+rr]       + s_p[1536+col*2+rr];
      float s1 = s_a1b2[256+col] + s_p[(256+col)*2+rr] + s_p[1536+(256+col)*2+rr];
      float s2 = s_a1b2[512+col] + s_p[(512+col)*2+rr] + s_p[1536+(512+col)*2+rr];
      float mx=fmaxf(fmaxf(s0,s1),s2);
      for (int off=32; off; off>>=1) mx=fmaxf(mx,__shfl_down(mx,off));
      if ((tid&63)==0) s_red[tid>>6]=mx;
      __syncthreads();                             // B6
      float m = fmaxf(fmaxf(s_red[rr*4],s_red[rr*4+1]),fmaxf(s_red[rr*4+2],s_red[rr*4+3]));
      float e0=expf(s0-m), e1=expf(s1-m), e2=expf(s2-m);
      float ss=e0+e1+e2;
      for (int off=32; off; off>>=1) ss+=__shfl_down(ss,off);
      if ((tid&63)==0) s_red[8+(tid>>6)]=ss;
      s_attm[(768+col)*2+rr] = s_mem[rr*256+col];
      __syncthreads();                             // B7
      float inv=1.f/(s_red[8+rr*4]+s_red[8+rr*4+1]+s_red[8+rr*4+2]+s_red[8+rr*4+3]);
      s_attm[col*2+rr]       = e0*inv*s_cstar[col*2+rr];
      s_attm[(256+col)*2+rr] = e1*inv*s_cstar[(256+col)*2+rr];
      s_attm[(512+col)*2+rr] = e2*inv*s_cstar[(512+col)*2+rr];
    }
    __syncthreads();                               // B8

    // ================ P7: a2w1 (K=768) / g1w1,g2w1 (K=1024), 2-way kh ================
    {
      float a0,a1;
      a0=0.f;a1=0.f;
      sweep<48,256>((const uint4*)p.a2w1 + (kh*48*256 + col), &s_attm[kh*768], a0,a1);
      *(v2f*)&s_p[kh*512 + col*2] = (v2f){a0,a1};
      a0=0.f;a1=0.f;
      sweep<64,256>((const uint4*)p.g1w1 + (kh*64*256 + col), &s_attm[kh*1024], a0,a1);
      *(v2f*)&s_p[1024 + kh*512 + col*2] = (v2f){a0,a1};
      a0=0.f;a1=0.f;
      sweep<64,256>((const uint4*)p.g2w1 + (kh*64*256 + col), &s_attm[kh*1024], a0,a1);
      *(v2f*)&s_p[2048 + kh*512 + col*2] = (v2f){a0,a1};
    }
    __syncthreads();                               // B9

    // ================ P8: z2 finalize (1536 tasks) ================
    for (int i=tid;i<1536;i+=512){
      int mat=i>>9, rem=i&511, c2=rem>>1, r=rem&1;
      const float* q = s_p + mat*1024;
      float v = s_b6[mat][c2] + q[c2*2+r] + q[512+c2*2+r];
      s_z2[(mat*256+c2)*2+r] = fmaxf(v,0.f);
    }
    __syncthreads();                               // B10

    // ================ P9: a2w2/g1w2/g2w2 (K=256 each, 2-way kh) ================
    {
      float a0,a1;
      a0=0.f;a1=0.f;
      sweep<16,256>((const uint4*)p.a2w2 + (kh*16*256 + col), &s_z2[kh*256], a0,a1);
      *(v2f*)&s_p[kh*512 + col*2] = (v2f){a0,a1};
      a0=0.f;a1=0.f;
      sweep<16,256>((const uint4*)p.g1w2 + (kh*16*256 + col), &s_z2[512+kh*256], a0,a1);
      *(v2f*)&s_p[1024 + kh*512 + col*2] = (v2f){a0,a1};
      a0=0.f;a1=0.f;
      sweep<16,256>((const uint4*)p.g2w2 + (kh*16*256 + col), &s_z2[1024+kh*256], a0,a1);
      *(v2f*)&s_p[2048 + kh*512 + col*2] = (v2f){a0,a1};
    }
    __syncthreads();                               // B11

    // ================ P10: mem update + x(t+1) refresh ================
    {
      float ch  = s_b6[3][col] + s_p[col*2+rr]      + s_p[512+col*2+rr];
      float gm1 = s_b6[4][col] + s_p[1024+col*2+rr] + s_p[1536+col*2+rr];
      float gm2 = s_b6[5][col] + s_p[2048+col*2+rr] + s_p[2560+col*2+rr];
      float mo = s_mem[rr*256+col];
      s_mem[rr*256+col] = sigf(gm1)*mo + sigf(gm2)*tanhf(ch);
    }
    if (t+1 < TSTEPS){
      const float* __restrict__ xb = p.x + (size_t)(t+1)*NBATCH*DX;
      int f0 = xfeat(tid>>1);
      if (f0>=0) s_x2[tid] = xb[(size_t)(n0+(tid&1))*DX + f0];
      int i2 = tid+512;
      if (i2 < 960){
        int f1 = xfeat(i2>>1);
        if (f1>=0) s_x2[i2] = xb[(size_t)(n0+(i2&1))*DX + f1];
      }
    }
    __syncthreads();                               // B12
  }

  // ================ output MLP (K=640, 2-way kh) ================
  for (int i=tid;i<1280;i+=512){
    int j=i>>1, r=i&1;
    float v = (j<384)? s_h2[j>>7][(j&127)*2+r] : s_mem[r*256 + (j-384)];
    s_last[i]=v;
  }
  __syncthreads();
  {
    float a0=0.f,a1=0.f;
    sweep<40,256>((const uint4*)p.ow1 + (kh*40*256 + col), &s_last[kh*640], a0,a1);
    *(v2f*)&s_p[kh*512 + col*2] = (v2f){a0,a1};
  }
  __syncthreads();
  {
    float z = p.ob1[col] + s_p[col*2+rr] + s_p[512+col*2+rr];
    float pp = fmaxf(z,0.f)*p.ow2[col];
    for (int off=32; off; off>>=1) pp+=__shfl_down(pp,off);
    if ((tid&63)==0) s_red[tid>>6]=pp;
    __syncthreads();
    if (tid==0)   p.out[n0]   = s_red[0]+s_red[1]+s_red[2]+s_red[3]+p.ob2[0];
    if (tid==256) p.out[n0+1] = s_red[4]+s_red[5]+s_red[6]+s_red[7]+p.ob2[0];
  }
}

extern "C" void kernel_launch(void* const* d_in, const int* in_sizes, int n_in,
                              void* d_out, int out_size, void* d_ws, size_t ws_size,
                              hipStream_t stream){
  u16* ws = (u16*)d_ws;
  struct M { int src; size_t off; int OUT, IN, INP; };
  const M mats[15] = {
    { 5,       0, 512,  300, 320},  // Wih_l
    { 6,  163840, 512,  128, 128},  // Whh_l
    { 9,  229376, 512,   74,  96},  // Wih_a
    {10,  278528, 512,  128, 128},  // Whh_a
    {13,  344064, 512,   35,  64},  // Wih_v
    {14,  376832, 512,  128, 128},  // Whh_v
    {17,  442368, 256,  768, 768},  // att1_W1
    {19,  638976, 768,  256, 256},  // att1_W2
    {21,  835584, 256,  768, 768},  // att2_W1
    {23, 1032192, 256,  256, 256},  // att2_W2
    {25, 1097728, 256, 1024,1024},  // g1_W1
    {27, 1359872, 256,  256, 256},  // g1_W2
    {29, 1425408, 256, 1024,1024},  // g2_W1
    {31, 1687552, 256,  256, 256},  // g2_W2
    {33, 1753088, 256,  640, 640},  // out_W1
  };
  for (int i=0;i<15;i++){
    int total = mats[i].OUT*mats[i].INP;
    cast_tile8<<<(total+255)/256, 256, 0, stream>>>(
        (const float*)d_in[mats[i].src], ws + mats[i].off,
        mats[i].OUT, mats[i].IN, mats[i].INP);
  }

  P p;
  p.x     = (const float*)d_in[0];
  p.bih_l = (const float*)d_in[7];  p.bhh_l = (const float*)d_in[8];
  p.bih_a = (const float*)d_in[11]; p.bhh_a = (const float*)d_in[12];
  p.bih_v = (const float*)d_in[15]; p.bhh_v = (const float*)d_in[16];
  p.a1b1  = (const float*)d_in[18]; p.a1b2  = (const float*)d_in[20];
  p.a2b1  = (const float*)d_in[22]; p.a2b2  = (const float*)d_in[24];
  p.g1b1  = (const float*)d_in[26]; p.g1b2  = (const float*)d_in[28];
  p.g2b1  = (const float*)d_in[30]; p.g2b2  = (const float*)d_in[32];
  p.ob1   = (const float*)d_in[34]; p.ow2   = (const float*)d_in[35];
  p.ob2   = (const float*)d_in[36];
  p.ihl   = ws + 0;       p.hhl  = ws + 163840;
  p.iha   = ws + 229376;  p.hha  = ws + 278528;
  p.ihv   = ws + 344064;  p.hhv  = ws + 376832;
  p.a1w1  = ws + 442368;  p.a1w2 = ws + 638976;
  p.a2w1  = ws + 835584;  p.a2w2 = ws + 1032192;
  p.g1w1  = ws + 1097728; p.g1w2 = ws + 1359872;
  p.g2w1  = ws + 1425408; p.g2w2 = ws + 1687552;
  p.ow1   = ws + 1753088;
  p.out   = (float*)d_out;

  mfn_persistent<<<NBATCH/2, 512, 0, stream>>>(p);
}

// Round 11
// 46843.378 us; speedup vs baseline: 1.3174x; 1.3174x over previous
//
#include <hip/hip_runtime.h>
#include <math.h>

#define TSTEPS 512
#define NBATCH 256
#define DLL 300
#define DAA 74
#define DVV 35
#define DX  409
#define DH  128
#define DMEM 256
#define CST 768   // 6*DH

typedef unsigned short u16;
typedef unsigned int   u32;
typedef float v2f __attribute__((ext_vector_type(2)));

__device__ __forceinline__ float ulo(u32 u){ return __uint_as_float(u<<16); }
__device__ __forceinline__ float uhi(u32 u){ return __uint_as_float(u & 0xffff0000u); }
__device__ __forceinline__ float sigf(float x){ return 1.0f/(1.0f+expf(-x)); }

// 8k-tiled: dst[(kb*OUT + o)*8 + j] = bf16(src[o*IN + kb*8+j]) or 0 pad
__global__ void cast_tile8(const float* __restrict__ src, u16* __restrict__ dst,
                           int OUT, int IN, int INP){
  int e = blockIdx.x*blockDim.x + threadIdx.x;
  if (e >= OUT*INP) return;
  int j = e & 7;
  int q = e >> 3;
  int o = q % OUT;
  int kb = q / OUT;
  int k = kb*8 + j;
  float v = (k < IN) ? src[o*IN + k] : 0.f;
  u32 u = __float_as_uint(v);
  u32 r = (u + 0x7fffu + ((u>>16)&1u)) >> 16;   // RNE
  dst[e] = (u16)r;
}

struct P {
  const float* x;
  const float *bih_l,*bhh_l,*bih_a,*bhh_a,*bih_v,*bhh_v;
  const float *a1b1,*a1b2,*a2b1,*a2b2,*g1b1,*g1b2,*g2b1,*g2b2;
  const float *ob1,*ow2,*ob2;
  const u16 *ihl,*hhl,*iha,*hha,*ihv,*hhv;
  const u16 *a1w1,*a1w2,*a2w1,*a2w2,*g1w1,*g1w2,*g2w1,*g2w2,*ow1;
  float* out;
};

// one 8k tile: 8 bf16 weights (one col) x acts[16] (8k x 2 rows interleaved) -> 2 accs
__device__ __forceinline__ void kb16(uint4 w, const float* __restrict__ ap,
                                     float &a0, float &a1){
  float4 x0=*(const float4*)ap, x1=*(const float4*)(ap+4),
         x2=*(const float4*)(ap+8), x3=*(const float4*)(ap+12);
  a0 += x0.x*ulo(w.x); a1 += x0.y*ulo(w.x);
  a0 += x0.z*uhi(w.x); a1 += x0.w*uhi(w.x);
  a0 += x1.x*ulo(w.y); a1 += x1.y*ulo(w.y);
  a0 += x1.z*uhi(w.y); a1 += x1.w*uhi(w.y);
  a0 += x2.x*ulo(w.z); a1 += x2.y*ulo(w.z);
  a0 += x2.z*uhi(w.z); a1 += x2.w*uhi(w.z);
  a0 += x3.x*ulo(w.w); a1 += x3.y*ulo(w.w);
  a0 += x3.z*uhi(w.w); a1 += x3.w*uhi(w.w);
}

// depth-8 modulo-scheduled ring, single-tile granularity, static reg names.
// Each W-slot is reloaded with the tile 8 ahead right after its compute:
// issue->consume distance = 7 tile-computes (~560 cy), 8 loads in flight,
// peak live = 8 uint4 (no spill at the 128-VGPR cap). NKB % 8 == 0, NKB >= 8.
template<int NKB, int WS>
__device__ __forceinline__ void sweep(const uint4* __restrict__ wp,
                                      const float* __restrict__ base,
                                      float &a0, float &a1){
  static_assert(NKB >= 8 && (NKB & 7) == 0, "NKB must be multiple of 8");
  uint4 W0=wp[0],    W1=wp[WS],   W2=wp[2*WS], W3=wp[3*WS],
        W4=wp[4*WS], W5=wp[5*WS], W6=wp[6*WS], W7=wp[7*WS];
  const uint4* wn = wp + 8*WS;
  int kb = 0;
  #pragma unroll 1
  for (; kb+8 < NKB; kb += 8){
    kb16(W0, base+(kb+0)*16, a0,a1); W0 = wn[0];
    kb16(W1, base+(kb+1)*16, a0,a1); W1 = wn[WS];
    kb16(W2, base+(kb+2)*16, a0,a1); W2 = wn[2*WS];
    kb16(W3, base+(kb+3)*16, a0,a1); W3 = wn[3*WS];
    kb16(W4, base+(kb+4)*16, a0,a1); W4 = wn[4*WS];
    kb16(W5, base+(kb+5)*16, a0,a1); W5 = wn[5*WS];
    kb16(W6, base+(kb+6)*16, a0,a1); W6 = wn[6*WS];
    kb16(W7, base+(kb+7)*16, a0,a1); W7 = wn[7*WS];
    wn += 8*WS;
  }
  kb16(W0, base+(kb+0)*16, a0,a1);
  kb16(W1, base+(kb+1)*16, a0,a1);
  kb16(W2, base+(kb+2)*16, a0,a1);
  kb16(W3, base+(kb+3)*16, a0,a1);
  kb16(W4, base+(kb+4)*16, a0,a1);
  kb16(W5, base+(kb+5)*16, a0,a1);
  kb16(W6, base+(kb+6)*16, a0,a1);
  kb16(W7, base+(kb+7)*16, a0,a1);
}

// padded x index -> feature index (or -1 for pad). L:[0,320) A:[320,448) V:[448,512)
__device__ __forceinline__ int xfeat(int i){
  if (i < 300) return i;
  if (i < 320) return -1;
  if (i < 394) return i-20;
  if (i < 448) return -1;
  if (i < 483) return i-74;
  return -1;
}

__global__ void __launch_bounds__(512, 2)
mfn_persistent(P p){
  __shared__ __align__(16) float s_x2[1024];     // [i*2+r], i<512 padded (pads stay 0)
  __shared__ __align__(16) float s_h2[3][256];   // [m][u*2+r]
  __shared__ __align__(16) float s_c2[3][256];
  __shared__ __align__(16) float s_cstar[1536];  // [idx*2+r]
  __shared__ __align__(16) float s_z[512];       // [k*2+r]
  __shared__ __align__(16) float s_attm[2048];   // [idx*2+r], idx<1024 (att768|mem256)
  __shared__ __align__(16) float s_z2[1536];     // [(mat*256+col)*2+r]
  __shared__ __align__(16) float s_mem[512];     // [r*256+col]
  __shared__ __align__(16) float s_p[3072];      // gates / partials
  __shared__ __align__(16) float s_last[1280];   // [j*2+r]
  __shared__ __align__(16) float s_a1b1[256];
  __shared__ __align__(16) float s_a1b2[768];
  __shared__ __align__(16) float s_b6[6][256];   // a2b1,g1b1,g2b1,a2b2,g1b2,g2b2
  __shared__ float s_red[16];

  const int tid = threadIdx.x;
  const int n0  = blockIdx.x*2;
  const int col = tid&255, rr = tid>>8, kh = tid>>8;

  // LSTM biases in registers (1 col/thread in P1)
  const float bLg = p.bih_l[tid]+p.bhh_l[tid];
  const float bAg = p.bih_a[tid]+p.bhh_a[tid];
  const float bVg = p.bih_v[tid]+p.bhh_v[tid];

  // ---- init ----
  if (tid < 256){
    s_a1b1[tid]=p.a1b1[tid];
    s_b6[0][tid]=p.a2b1[tid]; s_b6[1][tid]=p.g1b1[tid]; s_b6[2][tid]=p.g2b1[tid];
    s_b6[3][tid]=p.a2b2[tid]; s_b6[4][tid]=p.g1b2[tid]; s_b6[5][tid]=p.g2b2[tid];
  }
  for (int i=tid;i<768;i+=512){
    s_a1b2[i]=p.a1b2[i];
    (&s_h2[0][0])[i]=0.f; (&s_c2[0][0])[i]=0.f;
  }
  s_mem[tid]=0.f;
  for (int i2=tid;i2<1024;i2+=512){
    float v=0.f; int f=xfeat(i2>>1);
    if (f>=0) v = p.x[(size_t)(n0+(i2&1))*DX + f];
    s_x2[i2]=v;
  }
  __syncthreads();

  for (int t=0; t<TSTEPS; t++){
    // ================ P1: LSTM gates (1 col/thread, coherent full-K sweeps) ========
    {
      float a0,a1;
      a0=0.f; a1=0.f;
      sweep<40,512>((const uint4*)p.ihl + tid, &s_x2[0],   a0,a1);
      sweep<16,512>((const uint4*)p.hhl + tid, &s_h2[0][0],a0,a1);
      *(v2f*)&s_p[tid*2] = (v2f){a0+bLg, a1+bLg};
      a0=0.f; a1=0.f;
      sweep<16,512>((const uint4*)p.iha + tid, &s_x2[640], a0,a1);
      sweep<16,512>((const uint4*)p.hha + tid, &s_h2[1][0],a0,a1);
      *(v2f*)&s_p[1024 + tid*2] = (v2f){a0+bAg, a1+bAg};
      a0=0.f; a1=0.f;
      sweep< 8,512>((const uint4*)p.ihv + tid, &s_x2[896], a0,a1);
      sweep<16,512>((const uint4*)p.hhv + tid, &s_h2[2][0],a0,a1);
      *(v2f*)&s_p[2048 + tid*2] = (v2f){a0+bVg, a1+bVg};
    }
    __syncthreads();                               // B1

    // ================ P2: LSTM activations (768 tasks) ================
    for (int task=tid; task<768; task+=512){
      int m=task>>8, rem=task&255, u=rem>>1, r=rem&1;
      const float* pm = s_p + m*1024;
      float g0 = pm[u*2+r];
      float g1 = pm[(128+u)*2+r];
      float g2 = pm[(256+u)*2+r];
      float g3 = pm[(384+u)*2+r];
      float ig=sigf(g0), fg=sigf(g1), gg=tanhf(g2), og=sigf(g3);
      float co=s_c2[m][u*2+r];
      float c = fg*co + ig*gg;
      float h = og*tanhf(c);
      s_c2[m][u*2+r]=c; s_h2[m][u*2+r]=h;
      s_cstar[(m*128+u)*2+r]     = co;
      s_cstar[(384+m*128+u)*2+r] = c;
    }
    __syncthreads();                               // B2

    // ================ P3: att1_W1 (K=768, OUT=256, 2-way kh split) ================
    {
      float a0=0.f,a1=0.f;
      sweep<48,256>((const uint4*)p.a1w1 + (kh*48*256 + col), &s_cstar[kh*768], a0,a1);
      *(v2f*)&s_p[kh*512 + col*2] = (v2f){a0,a1};
    }
    __syncthreads();                               // B3

    // ================ P4: z1 finalize ================
    {
      float z = s_a1b1[col] + s_p[col*2+rr] + s_p[512+col*2+rr];
      s_z[col*2+rr] = fmaxf(z,0.f);
    }
    __syncthreads();                               // B4

    // ================ P5: att1_W2 (K=256, OUT=768; 3 sequential col-streams) ========
    {
      const uint4* wb=(const uint4*)p.a1w2 + (kh*16*768 + col);
      const float* base=&s_z[kh*256];
      float a0=0.f,a1=0.f,b0=0.f,b1=0.f,c0=0.f,c1=0.f;
      sweep<16,768>(wb,     base, a0,a1);
      sweep<16,768>(wb+256, base, b0,b1);
      sweep<16,768>(wb+512, base, c0,c1);
      *(v2f*)&s_p[kh*1536 + col*2]         = (v2f){a0,a1};
      *(v2f*)&s_p[kh*1536 + (256+col)*2]   = (v2f){b0,b1};
      *(v2f*)&s_p[kh*1536 + (512+col)*2]   = (v2f){c0,c1};
    }
    __syncthreads();                               // B5

    // ================ softmax + attended ================
    {
      float s0 = s_a1b2[col]     + s_p[col*2+rr]       + s_p[1536+col*2+rr];
      float s1 = s_a1b2[256+col] + s_p[(256+col)*2+rr] + s_p[1536+(256+col)*2+rr];
      float s2 = s_a1b2[512+col] + s_p[(512+col)*2+rr] + s_p[1536+(512+col)*2+rr];
      float mx=fmaxf(fmaxf(s0,s1),s2);
      for (int off=32; off; off>>=1) mx=fmaxf(mx,__shfl_down(mx,off));
      if ((tid&63)==0) s_red[tid>>6]=mx;
      __syncthreads();                             // B6
      float m = fmaxf(fmaxf(s_red[rr*4],s_red[rr*4+1]),fmaxf(s_red[rr*4+2],s_red[rr*4+3]));
      float e0=expf(s0-m), e1=expf(s1-m), e2=expf(s2-m);
      float ss=e0+e1+e2;
      for (int off=32; off; off>>=1) ss+=__shfl_down(ss,off);
      if ((tid&63)==0) s_red[8+(tid>>6)]=ss;
      s_attm[(768+col)*2+rr] = s_mem[rr*256+col];
      __syncthreads();                             // B7
      float inv=1.f/(s_red[8+rr*4]+s_red[8+rr*4+1]+s_red[8+rr*4+2]+s_red[8+rr*4+3]);
      s_attm[col*2+rr]       = e0*inv*s_cstar[col*2+rr];
      s_attm[(256+col)*2+rr] = e1*inv*s_cstar[(256+col)*2+rr];
      s_attm[(512+col)*2+rr] = e2*inv*s_cstar[(512+col)*2+rr];
    }
    __syncthreads();                               // B8

    // ================ P7: a2w1 (K=768) / g1w1,g2w1 (K=1024), 2-way kh ================
    {
      float a0,a1;
      a0=0.f;a1=0.f;
      sweep<48,256>((const uint4*)p.a2w1 + (kh*48*256 + col), &s_attm[kh*768], a0,a1);
      *(v2f*)&s_p[kh*512 + col*2] = (v2f){a0,a1};
      a0=0.f;a1=0.f;
      sweep<64,256>((const uint4*)p.g1w1 + (kh*64*256 + col), &s_attm[kh*1024], a0,a1);
      *(v2f*)&s_p[1024 + kh*512 + col*2] = (v2f){a0,a1};
      a0=0.f;a1=0.f;
      sweep<64,256>((const uint4*)p.g2w1 + (kh*64*256 + col), &s_attm[kh*1024], a0,a1);
      *(v2f*)&s_p[2048 + kh*512 + col*2] = (v2f){a0,a1};
    }
    __syncthreads();                               // B9

    // ================ P8: z2 finalize (1536 tasks) ================
    for (int i=tid;i<1536;i+=512){
      int mat=i>>9, rem=i&511, c2=rem>>1, r=rem&1;
      const float* q = s_p + mat*1024;
      float v = s_b6[mat][c2] + q[c2*2+r] + q[512+c2*2+r];
      s_z2[(mat*256+c2)*2+r] = fmaxf(v,0.f);
    }
    __syncthreads();                               // B10

    // ================ P9: a2w2/g1w2/g2w2 (K=256 each, 2-way kh) ================
    {
      float a0,a1;
      a0=0.f;a1=0.f;
      sweep<16,256>((const uint4*)p.a2w2 + (kh*16*256 + col), &s_z2[kh*256], a0,a1);
      *(v2f*)&s_p[kh*512 + col*2] = (v2f){a0,a1};
      a0=0.f;a1=0.f;
      sweep<16,256>((const uint4*)p.g1w2 + (kh*16*256 + col), &s_z2[512+kh*256], a0,a1);
      *(v2f*)&s_p[1024 + kh*512 + col*2] = (v2f){a0,a1};
      a0=0.f;a1=0.f;
      sweep<16,256>((const uint4*)p.g2w2 + (kh*16*256 + col), &s_z2[1024+kh*256], a0,a1);
      *(v2f*)&s_p[2048 + kh*512 + col*2] = (v2f){a0,a1};
    }
    __syncthreads();                               // B11

    // ================ P10: mem update + x(t+1) refresh ================
    {
      float ch  = s_b6[3][col] + s_p[col*2+rr]      + s_p[512+col*2+rr];
      float gm1 = s_b6[4][col] + s_p[1024+col*2+rr] + s_p[1536+col*2+rr];
      float gm2 = s_b6[5][col] + s_p[2048+col*2+rr] + s_p[2560+col*2+rr];
      float mo = s_mem[rr*256+col];
      s_mem[rr*256+col] = sigf(gm1)*mo + sigf(gm2)*tanhf(ch);
    }
    if (t+1 < TSTEPS){
      const float* __restrict__ xb = p.x + (size_t)(t+1)*NBATCH*DX;
      int f0 = xfeat(tid>>1);
      if (f0>=0) s_x2[tid] = xb[(size_t)(n0+(tid&1))*DX + f0];
      int i2 = tid+512;
      int f1 = xfeat(i2>>1);
      if (f1>=0) s_x2[i2] = xb[(size_t)(n0+(i2&1))*DX + f1];
    }
    __syncthreads();                               // B12
  }

  // ================ output MLP (K=640, 2-way kh) ================
  for (int i=tid;i<1280;i+=512){
    int j=i>>1, r=i&1;
    float v = (j<384)? s_h2[j>>7][(j&127)*2+r] : s_mem[r*256 + (j-384)];
    s_last[i]=v;
  }
  __syncthreads();
  {
    float a0=0.f,a1=0.f;
    sweep<40,256>((const uint4*)p.ow1 + (kh*40*256 + col), &s_last[kh*640], a0,a1);
    *(v2f*)&s_p[kh*512 + col*2] = (v2f){a0,a1};
  }
  __syncthreads();
  {
    float z = p.ob1[col] + s_p[col*2+rr] + s_p[512+col*2+rr];
    float pp = fmaxf(z,0.f)*p.ow2[col];
    for (int off=32; off; off>>=1) pp+=__shfl_down(pp,off);
    if ((tid&63)==0) s_red[tid>>6]=pp;
    __syncthreads();
    if (tid==0)   p.out[n0]   = s_red[0]+s_red[1]+s_red[2]+s_red[3]+p.ob2[0];
    if (tid==256) p.out[n0+1] = s_red[4]+s_red[5]+s_red[6]+s_red[7]+p.ob2[0];
  }
}

extern "C" void kernel_launch(void* const* d_in, const int* in_sizes, int n_in,
                              void* d_out, int out_size, void* d_ws, size_t ws_size,
                              hipStream_t stream){
  u16* ws = (u16*)d_ws;
  struct M { int src; size_t off; int OUT, IN, INP; };
  const M mats[15] = {
    { 5,       0, 512,  300, 320},  // Wih_l
    { 6,  163840, 512,  128, 128},  // Whh_l
    { 9,  229376, 512,   74, 128},  // Wih_a (padded to NKB=16)
    {10,  294912, 512,  128, 128},  // Whh_a
    {13,  360448, 512,   35,  64},  // Wih_v
    {14,  393216, 512,  128, 128},  // Whh_v
    {17,  458752, 256,  768, 768},  // att1_W1
    {19,  655360, 768,  256, 256},  // att1_W2
    {21,  851968, 256,  768, 768},  // att2_W1
    {23, 1048576, 256,  256, 256},  // att2_W2
    {25, 1114112, 256, 1024,1024},  // g1_W1
    {27, 1376256, 256,  256, 256},  // g1_W2
    {29, 1441792, 256, 1024,1024},  // g2_W1
    {31, 1703936, 256,  256, 256},  // g2_W2
    {33, 1769472, 256,  640, 640},  // out_W1
  };
  for (int i=0;i<15;i++){
    int total = mats[i].OUT*mats[i].INP;
    cast_tile8<<<(total+255)/256, 256, 0, stream>>>(
        (const float*)d_in[mats[i].src], ws + mats[i].off,
        mats[i].OUT, mats[i].IN, mats[i].INP);
  }

  P p;
  p.x     = (const float*)d_in[0];
  p.bih_l = (const float*)d_in[7];  p.bhh_l = (const float*)d_in[8];
  p.bih_a = (const float*)d_in[11]; p.bhh_a = (const float*)d_in[12];
  p.bih_v = (const float*)d_in[15]; p.bhh_v = (const float*)d_in[16];
  p.a1b1  = (const float*)d_in[18]; p.a1b2  = (const float*)d_in[20];
  p.a2b1  = (const float*)d_in[22]; p.a2b2  = (const float*)d_in[24];
  p.g1b1  = (const float*)d_in[26]; p.g1b2  = (const float*)d_in[28];
  p.g2b1  = (const float*)d_in[30]; p.g2b2  = (const float*)d_in[32];
  p.ob1   = (const float*)d_in[34]; p.ow2   = (const float*)d_in[35];
  p.ob2   = (const float*)d_in[36];
  p.ihl   = ws + 0;       p.hhl  = ws + 163840;
  p.iha   = ws + 229376;  p.hha  = ws + 294912;
  p.ihv   = ws + 360448;  p.hhv  = ws + 393216;
  p.a1w1  = ws + 458752;  p.a1w2 = ws + 655360;
  p.a2w1  = ws + 851968;  p.a2w2 = ws + 1048576;
  p.g1w1  = ws + 1114112; p.g1w2 = ws + 1376256;
  p.g2w1  = ws + 1441792; p.g2w2 = ws + 1703936;
  p.ow1   = ws + 1769472;
  p.out   = (float*)d_out;

  mfn_persistent<<<NBATCH/2, 512, 0, stream>>>(p);
}